// Round 3
// baseline (12886.302 us; speedup 1.0000x reference)
//
#include <hip/hip_runtime.h>
#include <hip/hip_cooperative_groups.h>

namespace cg = cooperative_groups;

typedef short s16x8 __attribute__((ext_vector_type(8)));
typedef float f32x4 __attribute__((ext_vector_type(4)));
typedef unsigned int u32x4 __attribute__((ext_vector_type(4)));
typedef unsigned int u32x2 __attribute__((ext_vector_type(2)));

#define B_ 64
#define T_ 512
#define D_ 1024
#define H_ 1024
#define TC_ 128   // time chunk

__device__ __forceinline__ unsigned short f2bf(float f) {
  union { float f; unsigned int u; } v; v.f = f;
  unsigned int r = v.u + 0x7fffu + ((v.u >> 16) & 1u);
  return (unsigned short)(r >> 16);
}
__device__ __forceinline__ float bf2f(unsigned short h) {
  union { unsigned int u; float f; } v; v.u = ((unsigned int)h) << 16;
  return v.f;
}

// ---- convert W_ih and W_hh fp32 -> bf16 (n = 3*1024*1024 each) ----
__global__ __launch_bounds__(256) void k_cvt_w(const float* __restrict__ w1, unsigned short* __restrict__ o1,
                                               const float* __restrict__ w2, unsigned short* __restrict__ o2) {
  int i = (blockIdx.x * 256 + threadIdx.x) * 4;
  float4 a = *(const float4*)(w1 + i);
  u32x2 p;
  p.x = (unsigned)f2bf(a.x) | ((unsigned)f2bf(a.y) << 16);
  p.y = (unsigned)f2bf(a.z) | ((unsigned)f2bf(a.w) << 16);
  *(u32x2*)(o1 + i) = p;
  float4 b = *(const float4*)(w2 + i);
  u32x2 q;
  q.x = (unsigned)f2bf(b.x) | ((unsigned)f2bf(b.y) << 16);
  q.y = (unsigned)f2bf(b.z) | ((unsigned)f2bf(b.w) << 16);
  *(u32x2*)(o2 + i) = q;
}

// ---- x [B][T][D] fp32 -> xt [(tl*64+b)][D] bf16 for t in [t0, t0+TC_) ----
__global__ __launch_bounds__(256) void k_xt(const float* __restrict__ x, unsigned short* __restrict__ xt, int t0) {
  int m = blockIdx.x;              // m = tl*64 + b, tl in [0,TC_)
  int t = t0 + (m >> 6), b = m & 63;
  const float* src = x + ((size_t)(b * T_ + t)) * D_;
  unsigned short* dst = xt + (size_t)m * D_;
  int d = threadIdx.x * 4;
  float4 a = *(const float4*)(src + d);
  u32x2 p;
  p.x = (unsigned)f2bf(a.x) | ((unsigned)f2bf(a.y) << 16);
  p.y = (unsigned)f2bf(a.z) | ((unsigned)f2bf(a.w) << 16);
  *(u32x2*)(dst + d) = p;
}

// ---- h0 -> hbuf16[0] (bf16) + hbuf32[0] (fp32); dones [B][T] -> maskT [T][B] float ----
__global__ __launch_bounds__(256) void k_misc(const float* __restrict__ h0, const int* __restrict__ dones,
                                              unsigned short* __restrict__ hb16, float* __restrict__ hb32,
                                              float* __restrict__ maskT) {
  int i = blockIdx.x * 256 + threadIdx.x;  // 65536 threads = B*H
  float v = h0[i];
  hb16[i] = f2bf(v);
  hb32[i] = v;
  if (i < T_ * B_) {
    int t = i >> 6, b = i & 63;
    maskT[i] = dones[b * T_ + t] ? 0.f : 1.f;
  }
}

// ---- gi = xt @ W_ih^T + b_ih ; A[M=8192][K=1024], B[N=3072][K=1024], C[m][n] bf16 ----
__global__ __launch_bounds__(256) void k_gemm(const unsigned short* __restrict__ A,
                                              const unsigned short* __restrict__ Bm,
                                              const float* __restrict__ bias,
                                              unsigned short* __restrict__ C) {
  __shared__ __align__(16) unsigned short As[128 * 40];  // 32 k-shorts + 8 pad (2-way aliasing: free)
  __shared__ __align__(16) unsigned short Bs[128 * 40];
  const int tid = threadIdx.x;
  const int wave = tid >> 6, lane = tid & 63;
  const int q = lane >> 4, r = lane & 15;
  const int wm = wave >> 1, wn = wave & 1;
  const long m0 = (long)blockIdx.y * 128, n0 = (long)blockIdx.x * 128;
  f32x4 acc[4][4] = {};
  for (int k0 = 0; k0 < 1024; k0 += 32) {
    __syncthreads();
#pragma unroll
    for (int c0 = 0; c0 < 2; ++c0) {
      int c = c0 * 256 + tid;          // 512 16B-chunks (8 shorts each) per tile pair
      int row = c >> 2, kof = (c & 3) * 8;
      *(u32x4*)&As[row * 40 + kof] = *(const u32x4*)(A + (m0 + row) * 1024 + k0 + kof);
      *(u32x4*)&Bs[row * 40 + kof] = *(const u32x4*)(Bm + (n0 + row) * 1024 + k0 + kof);
    }
    __syncthreads();
    s16x8 af[4], bfr[4];
#pragma unroll
    for (int mt = 0; mt < 4; ++mt)
      af[mt] = *(const s16x8*)&As[(wm * 64 + mt * 16 + r) * 40 + q * 8];
#pragma unroll
    for (int nt = 0; nt < 4; ++nt)
      bfr[nt] = *(const s16x8*)&Bs[(wn * 64 + nt * 16 + r) * 40 + q * 8];
#pragma unroll
    for (int mt = 0; mt < 4; ++mt)
#pragma unroll
      for (int nt = 0; nt < 4; ++nt)
        acc[mt][nt] = __builtin_amdgcn_mfma_f32_16x16x32_bf16(af[mt], bfr[nt], acc[mt][nt], 0, 0, 0);
  }
#pragma unroll
  for (int nt = 0; nt < 4; ++nt) {
    long n = n0 + wn * 64 + nt * 16 + r;
    float bn = bias[n];
#pragma unroll
    for (int mt = 0; mt < 4; ++mt) {
#pragma unroll
      for (int reg = 0; reg < 4; ++reg) {
        long m = m0 + wm * 64 + mt * 16 + q * 4 + reg;  // C/D: col=lane&15, row=quad*4+reg
        C[m * 3072 + n] = f2bf(acc[mt][nt][reg] + bn);
      }
    }
  }
}

// ---- persistent recurrent kernel over one time chunk: 64 blocks x 256 threads ----
// block owns output cols j0..j0+15 (all 3 gates); W_hh slice resident in LDS.
__global__ __launch_bounds__(256) void k_gru(const unsigned short* __restrict__ whh,
                                             const float* __restrict__ bhh,
                                             const unsigned short* __restrict__ gi,
                                             const float* __restrict__ maskT,
                                             unsigned short* __restrict__ hb16,
                                             float* __restrict__ hb32,
                                             float* __restrict__ out,
                                             int t0) {
  __shared__ __align__(16) unsigned short Ws[3][16][1032];  // ~97 KB; +8 pad (2-way aliasing: free)
  cg::grid_group grid = cg::this_grid();
  const int tid = threadIdx.x;
  const int wave = tid >> 6, lane = tid & 63;
  const int q = lane >> 4, r = lane & 15;
  const int j0 = blockIdx.x * 16;
  float* hlast = out + (size_t)B_ * T_ * H_;

  // stage W_hh rows {g*1024 + j0..j0+15} into LDS once per chunk.
  // FIX (r2): u32x4 = 8 shorts, so segment stride is 8 shorts, 128 segs/row.
  for (int idx = tid; idx < 48 * 128; idx += 256) {
    int row = idx >> 7, seg = idx & 127;
    int g = row >> 4, l = row & 15;
    *(u32x4*)&Ws[g][l][seg * 8] =
        *(const u32x4*)(whh + ((size_t)(g * 1024 + j0 + l)) * 1024 + seg * 8);
  }
  const float bhr = bhh[j0 + r];
  const float bhz = bhh[1024 + j0 + r];
  const float bhn = bhh[2048 + j0 + r];
  __syncthreads();

  for (int tl = 0; tl < TC_; ++tl) {
    const int t = t0 + tl;
    const unsigned short* hs16 = hb16 + (size_t)(t & 1) * (B_ * H_);
    unsigned short* hd16 = hb16 + (size_t)((t + 1) & 1) * (B_ * H_);
    const float* hs32 = hb32 + (size_t)(t & 1) * (B_ * H_);
    float* hd32 = hb32 + (size_t)((t + 1) & 1) * (B_ * H_);
    const float mk = maskT[t * 64 + wave * 16 + r];  // mask for A-row b = wave*16 + r
    f32x4 acc0 = {0.f, 0.f, 0.f, 0.f};
    f32x4 acc1 = {0.f, 0.f, 0.f, 0.f};
    f32x4 acc2 = {0.f, 0.f, 0.f, 0.f};
    const unsigned short* arow = hs16 + (size_t)(wave * 16 + r) * 1024;
#pragma unroll 4
    for (int ks = 0; ks < 32; ++ks) {
      u32x4 av = *(const u32x4*)(arow + ks * 32 + q * 8);
      if (mk == 0.f) { av.x = 0; av.y = 0; av.z = 0; av.w = 0; }  // h_eff = h*mask feeds matvec
      s16x8 a = __builtin_bit_cast(s16x8, av);
      s16x8 b0 = *(const s16x8*)&Ws[0][r][ks * 32 + q * 8];
      s16x8 b1 = *(const s16x8*)&Ws[1][r][ks * 32 + q * 8];
      s16x8 b2 = *(const s16x8*)&Ws[2][r][ks * 32 + q * 8];
      acc0 = __builtin_amdgcn_mfma_f32_16x16x32_bf16(a, b0, acc0, 0, 0, 0);
      acc1 = __builtin_amdgcn_mfma_f32_16x16x32_bf16(a, b1, acc1, 0, 0, 0);
      acc2 = __builtin_amdgcn_mfma_f32_16x16x32_bf16(a, b2, acc2, 0, 0, 0);
    }
#pragma unroll
    for (int reg = 0; reg < 4; ++reg) {
      int b = wave * 16 + q * 4 + reg;       // C/D: col=lane&15, row=quad*4+reg
      size_t mrow = (size_t)(tl * 64 + b) * 3072;
      float gir = bf2f(gi[mrow + j0 + r]);
      float giz = bf2f(gi[mrow + 1024 + j0 + r]);
      float gin = bf2f(gi[mrow + 2048 + j0 + r]);
      float ghr = acc0[reg] + bhr;
      float ghz = acc1[reg] + bhz;
      float ghn = acc2[reg] + bhn;
      float rr = 1.f / (1.f + __expf(-(gir + ghr)));
      float zz = 1.f / (1.f + __expf(-(giz + ghz)));
      float nn = tanhf(gin + rr * ghn);
      float mb = maskT[t * 64 + b];
      float hp = hs32[(size_t)b * 1024 + j0 + r] * mb;   // fp32 h for the update path
      float hn = (1.f - zz) * nn + zz * hp;
      out[((size_t)b * 512 + t) * 1024 + j0 + r] = hn;
      hd16[(size_t)b * 1024 + j0 + r] = f2bf(hn);
      hd32[(size_t)b * 1024 + j0 + r] = hn;
      if (t == 511) hlast[(size_t)b * 1024 + j0 + r] = hn;
    }
    __threadfence();
    grid.sync();
  }
}

extern "C" void kernel_launch(void* const* d_in, const int* in_sizes, int n_in,
                              void* d_out, int out_size, void* d_ws, size_t ws_size,
                              hipStream_t stream) {
  const float* x     = (const float*)d_in[0];
  const float* h0    = (const float*)d_in[1];
  const int*   dones = (const int*)d_in[2];
  const float* Wih   = (const float*)d_in[3];
  const float* Whh   = (const float*)d_in[4];
  const float* bih   = (const float*)d_in[5];
  const float* bhh   = (const float*)d_in[6];
  float* out = (float*)d_out;
  char* ws = (char*)d_ws;
  // ws layout (total ~80.6 MB):
  unsigned short* wih_b = (unsigned short*)(ws);                  //  6 MB
  unsigned short* whh_b = (unsigned short*)(ws + 6291456);        //  6 MB
  unsigned short* xt_c  = (unsigned short*)(ws + 12582912);       // 16 MB (one chunk)
  unsigned short* gi_c  = (unsigned short*)(ws + 29360128);       // 48 MB (one chunk)
  float*          maskT = (float*)(ws + 79691776);                // 128 KB
  unsigned short* hb16  = (unsigned short*)(ws + 79822848);       // 256 KB (double buffer)
  float*          hb32  = (float*)(ws + 80085248);                // 512 KB (double buffer)

  k_cvt_w<<<3072, 256, 0, stream>>>(Wih, wih_b, Whh, whh_b);
  k_misc<<<256, 256, 0, stream>>>(h0, dones, hb16, hb32, maskT);

  for (int c = 0; c < 4; ++c) {
    int t0 = c * TC_;
    k_xt<<<TC_ * 64, 256, 0, stream>>>(x, xt_c, t0);
    k_gemm<<<dim3(24, TC_ * 64 / 128), 256, 0, stream>>>(xt_c, wih_b, bih, gi_c);
    void* args[] = {(void*)&whh_b, (void*)&bhh, (void*)&gi_c, (void*)&maskT,
                    (void*)&hb16, (void*)&hb32, (void*)&out, (void*)&t0};
    hipLaunchCooperativeKernel((const void*)k_gru, dim3(64), dim3(256), args, 0, stream);
  }
}